// Round 1
// baseline (47.733 us; speedup 1.0000x reference)
//
#include <hip/hip_runtime.h>
#include <math.h>

// QFF1: per point n, per freq f: enc[m=s*3+d] = {sin,cos}(p_d * freq_f)
// pos = (enc+1)*39.5 ; lerp into table qv[f*6+m][cr][q] (transposed to [q][cr] in LDS)
// out[n][ (f*2+s)*4 + c ] = sum_r prod_d lerp(m=s*3+d, cr=c*8+r)

constexpr int N_POINTS = 131072;
constexpr int NFREQ    = 6;
constexpr int QN       = 80;
constexpr int CRN      = 32;   // NUM_FEATS(4) * NUM_CORRS(8)
constexpr int M_PER_F  = 6;    // 2 (sin/cos) * 3 dims
constexpr int THREADS  = 512;
constexpr int PTS_PER_BLOCK = 512;

__global__ __launch_bounds__(THREADS, 4)
void qff1_kernel(const float* __restrict__ points,
                 const float* __restrict__ qff,
                 const float* __restrict__ freqs,
                 float* __restrict__ out)
{
    // [m][q][cr] with chunk rotation: logical float4-chunk j of row q lives at
    // physical chunk (j+q)&7 -> random rows spread over all 8 bank groups.
    __shared__ float lds[M_PER_F * QN * CRN];   // 61440 B -> 2 blocks/CU

    const int f = blockIdx.y;
    const float freq = freqs[f];

    // ---- stage this frequency's 6 tables (transpose [cr][q] -> [q][cr] + swizzle)
    const float* tab = qff + (size_t)f * (M_PER_F * CRN * QN);
    for (int idx = threadIdx.x; idx < M_PER_F * CRN * QN; idx += THREADS) {
        int m   = idx / (CRN * QN);
        int rem = idx - m * (CRN * QN);
        int cr  = rem / QN;
        int q   = rem - cr * QN;
        int chunk = ((cr >> 2) + q) & 7;
        lds[m * (QN * CRN) + q * CRN + chunk * 4 + (cr & 3)] = tab[idx];
    }
    __syncthreads();

    const int n = blockIdx.x * PTS_PER_BLOCK + threadIdx.x;

    const float px = points[n * 3 + 0];
    const float py = points[n * 3 + 1];
    const float pz = points[n * 3 + 2];

    float enc[6];
    {
        float s, c;
        __sincosf(px * freq, &s, &c); enc[0] = s; enc[3] = c;
        __sincosf(py * freq, &s, &c); enc[1] = s; enc[4] = c;
        __sincosf(pz * freq, &s, &c); enc[2] = s; enc[5] = c;
    }

    int   bi0[6], bi1[6], r0[6], r1[6];
    float w[6];
#pragma unroll
    for (int m = 0; m < 6; ++m) {
        float pos = (enc[m] + 1.0f) * 0.5f * (float)(QN - 1);
        float fi  = floorf(pos);
        int i0    = (int)fi;
        i0 = i0 < 0 ? 0 : (i0 > QN - 1 ? QN - 1 : i0);
        int i1 = i0 + 1; if (i1 > QN - 1) i1 = QN - 1;
        w[m]  = pos - (float)i0;
        r0[m] = i0;
        r1[m] = i1;
        bi0[m] = m * (QN * 8) + i0 * 8;   // float4 index into lds
        bi1[m] = m * (QN * 8) + i1 * 8;
    }

    const float4* lds4 = (const float4*)lds;
    float acc[8];
#pragma unroll
    for (int k = 0; k < 8; ++k) acc[k] = 0.0f;

#pragma unroll
    for (int s = 0; s < 2; ++s) {
#pragma unroll
        for (int j = 0; j < 8; ++j) {   // cr chunk of 4; c = j>>1
            float4 v[3];
#pragma unroll
            for (int d = 0; d < 3; ++d) {
                int m = s * 3 + d;
                float4 A = lds4[bi0[m] + ((j + r0[m]) & 7)];
                float4 B = lds4[bi1[m] + ((j + r1[m]) & 7)];
                float ww = w[m];
                v[d].x = fmaf(ww, B.x - A.x, A.x);
                v[d].y = fmaf(ww, B.y - A.y, A.y);
                v[d].z = fmaf(ww, B.z - A.z, A.z);
                v[d].w = fmaf(ww, B.w - A.w, A.w);
            }
            float sx = v[0].x * v[1].x * v[2].x;
            float sy = v[0].y * v[1].y * v[2].y;
            float sz = v[0].z * v[1].z * v[2].z;
            float sw = v[0].w * v[1].w * v[2].w;
            acc[s * 4 + (j >> 1)] += (sx + sy) + (sz + sw);
        }
    }

    float4* o = (float4*)(out + (size_t)n * 48 + f * 8);
    o[0] = make_float4(acc[0], acc[1], acc[2], acc[3]);
    o[1] = make_float4(acc[4], acc[5], acc[6], acc[7]);
}

extern "C" void kernel_launch(void* const* d_in, const int* in_sizes, int n_in,
                              void* d_out, int out_size, void* d_ws, size_t ws_size,
                              hipStream_t stream) {
    const float* points = (const float*)d_in[0];   // (131072, 3)
    const float* qff    = (const float*)d_in[1];   // (36, 32, 80, 1)
    const float* freqs  = (const float*)d_in[2];   // (6,)
    float* out = (float*)d_out;                    // (131072, 48)

    dim3 grid(N_POINTS / PTS_PER_BLOCK, NFREQ);
    dim3 block(THREADS);
    qff1_kernel<<<grid, block, 0, stream>>>(points, qff, freqs, out);
}